// Round 1
// baseline (1701.372 us; speedup 1.0000x reference)
//
#include <hip/hip_runtime.h>
#include <stdint.h>

// MSACrossAttention on MI355X (gfx950).
// R=64 L=512 B=4 E=768 H=12 D=64 QD=384
// Key algebra: attn logits sum over r commutes with Wk: ksum=(sum_r x)@Wk.T*scaling,
// and scaling*R == 1 so bias bk passes through unscaled.
// Pipeline:
//  1. k_wconv  : Wv,Wo -> bf16
//  2. k_xprep  : xsum = sum_r x (fp32) ; xbf = bf16(x)            [ws]
//  3. k_gemm_f32: q    = query@Wq.T + bq                          [ws]
//  4. k_gemm_f32: ksum = (1/64)*(xsum@Wk.T) + bk                  [ws]
//  5. k_logits_softmax: probs fp32 -> d_out, bf16 copy -> ws
//  6. k_gemm_v : V = xbf@Wv.T+bv, NATURAL [m][e] layout, bf16     [d_out scratch]
//  7. k_gemm_ctx: context = probs@V (per r,n,h slice), bf16       [ws, reuses xbf]
//     (j/d transpose done in LDS staging with XOR swizzle)
//  8. k_gemm_out: out = context@Wo.T + bo (fp32)                  [d_out]
// All bf16 GEMMs stage via global_load_lds width=16 (m193: +67% class lever).
// ws usage: 247,726,080 bytes.

#define R_ 64
#define L_ 512
#define B_ 4
#define E_ 768
#define H_ 12
#define D_ 64
#define P_ (L_*B_*E_)      // 1572864 elems per r-slice
#define MBIG_ (R_*L_*B_)   // 131072 rows
#define OUT0_ 100663296    // output elements (then probs)

typedef unsigned short u16;
typedef short short8 __attribute__((ext_vector_type(8)));
typedef float float4v __attribute__((ext_vector_type(4)));

__device__ __forceinline__ u16 f2bf(float f) {
  union { float f; uint32_t u; } v; v.f = f;
  return (u16)((v.u + 0x7fffu + ((v.u >> 16) & 1u)) >> 16);
}

// async global->LDS, 16B per lane. LDS dest must be wave-uniform-base + lane*16,
// which holds for all call sites here (lds byte offset = c*16, c lane-contiguous).
__device__ __forceinline__ void gload16(const u16* g, u16* lds) {
  __builtin_amdgcn_global_load_lds(
      (const __attribute__((address_space(1))) u16*)g,
      (__attribute__((address_space(3))) u16*)lds, 16, 0, 0);
}

// lB transpose swizzle for k_gemm_ctx: conflict-free on BOTH the transposed
// ds_write_b16 (d varies per lane: needs d>>3 mixed in, since d-stride 64 u16
// == 0 mod 32 dwords) and the ds_read_b128 (d = l16 varies: needs d&7 mixed in).
#define SWZB(d) ((((d) ^ ((d) >> 3)) & 7) << 3)

// ---------------- 1. weight convert ----------------
__global__ __launch_bounds__(256) void k_wconv(const float* __restrict__ Wv,
                                               const float* __restrict__ Wo,
                                               u16* __restrict__ Wvb,
                                               u16* __restrict__ Wob) {
  int i4 = (blockIdx.x * 256 + threadIdx.x) * 4;  // 589824 total, grid=576
  float4 v = *(const float4*)(Wv + i4);
  ushort4 b; b.x = f2bf(v.x); b.y = f2bf(v.y); b.z = f2bf(v.z); b.w = f2bf(v.w);
  *(ushort4*)(Wvb + i4) = b;
  float4 o = *(const float4*)(Wo + i4);
  ushort4 c; c.x = f2bf(o.x); c.y = f2bf(o.y); c.z = f2bf(o.z); c.w = f2bf(o.w);
  *(ushort4*)(Wob + i4) = c;
}

// ---------------- 2. x reduce-over-r + bf16 convert ----------------
__global__ __launch_bounds__(256) void k_xprep(const float* __restrict__ x,
                                               u16* __restrict__ xbf,
                                               float* __restrict__ xsum) {
  size_t p4 = ((size_t)blockIdx.x * 256 + threadIdx.x) * 4;  // grid=1536
  float sx = 0.f, sy = 0.f, sz = 0.f, sw = 0.f;
  for (int r = 0; r < R_; ++r) {
    float4 v = *(const float4*)(x + (size_t)r * P_ + p4);
    sx += v.x; sy += v.y; sz += v.z; sw += v.w;
    ushort4 b; b.x = f2bf(v.x); b.y = f2bf(v.y); b.z = f2bf(v.z); b.w = f2bf(v.w);
    *(ushort4*)(xbf + (size_t)r * P_ + p4) = b;
  }
  float4 s; s.x = sx; s.y = sy; s.z = sz; s.w = sw;
  *(float4*)(xsum + p4) = s;
}

// ---------------- 3/4. small fp32 GEMM: C = alpha*(A@W^T) + bias ----------------
// A[M][K], W[N][K], C[M][N]; block 64x64, BK=16, 256 thr, 4x4 per thread
__global__ __launch_bounds__(256) void k_gemm_f32(const float* __restrict__ A,
                                                  const float* __restrict__ W,
                                                  const float* __restrict__ bias,
                                                  float* __restrict__ C,
                                                  int M, int N, int K, float alpha) {
  __shared__ float sA[16][65], sW[16][65];
  const int t = threadIdx.x;
  const int col0 = blockIdx.x * 64, row0 = blockIdx.y * 64;
  const int tx = t & 15, ty = t >> 4;
  const int srow = t >> 2, sk4 = (t & 3) * 4;
  float acc[4][4] = {};
  for (int kt = 0; kt < K; kt += 16) {
    float4 va = *(const float4*)&A[(size_t)(row0 + srow) * K + kt + sk4];
    sA[sk4 + 0][srow] = va.x; sA[sk4 + 1][srow] = va.y;
    sA[sk4 + 2][srow] = va.z; sA[sk4 + 3][srow] = va.w;
    float4 vw = *(const float4*)&W[(size_t)(col0 + srow) * K + kt + sk4];
    sW[sk4 + 0][srow] = vw.x; sW[sk4 + 1][srow] = vw.y;
    sW[sk4 + 2][srow] = vw.z; sW[sk4 + 3][srow] = vw.w;
    __syncthreads();
#pragma unroll
    for (int k = 0; k < 16; ++k) {
      float ar[4], wr[4];
#pragma unroll
      for (int a = 0; a < 4; ++a) ar[a] = sA[k][ty + 16 * a];
#pragma unroll
      for (int b = 0; b < 4; ++b) wr[b] = sW[k][tx + 16 * b];
#pragma unroll
      for (int a = 0; a < 4; ++a)
#pragma unroll
        for (int b = 0; b < 4; ++b) acc[a][b] += ar[a] * wr[b];
    }
    __syncthreads();
  }
#pragma unroll
  for (int a = 0; a < 4; ++a)
#pragma unroll
    for (int b = 0; b < 4; ++b) {
      int col = col0 + tx + 16 * b;
      C[(size_t)(row0 + ty + 16 * a) * N + col] = alpha * acc[a][b] + bias[col];
    }
}

// ---------------- 5. logits + softmax ----------------
// block: (i-tile of 16) x (h,n). logits[i][j] = sum_d ksum[i,n,h,d]*q[j,n,h,d]
__global__ __launch_bounds__(256) void k_logits_softmax(const float* __restrict__ q,
                                                        const float* __restrict__ ksum,
                                                        float* __restrict__ probsF,
                                                        u16* __restrict__ probsB) {
  __shared__ float sk[16][65];
  __shared__ float sq[64][65];
  const int t = threadIdx.x;
  const int it = blockIdx.x;        // 0..31
  const int hn = blockIdx.y;        // 0..47 = h*4+n
  const int h = hn >> 2, n = hn & 3;
  const int ii = t >> 4, jx = t & 15;
  {
    const float* src = ksum + ((size_t)(it * 16 + ii) * 4 + n) * 768 + h * 64 + jx * 4;
    float4 v = *(const float4*)src;
    sk[ii][jx * 4 + 0] = v.x; sk[ii][jx * 4 + 1] = v.y;
    sk[ii][jx * 4 + 2] = v.z; sk[ii][jx * 4 + 3] = v.w;
  }
  float lg[32];
  for (int jt = 0; jt < 8; ++jt) {
#pragma unroll
    for (int p = 0; p < 4; ++p) {
      int c = p * 256 + t;
      int row = c >> 4, c4 = (c & 15) * 4;
      const float* src = q + ((size_t)(jt * 64 + row) * 4 + n) * 768 + h * 64 + c4;
      float4 v = *(const float4*)src;
      sq[row][c4 + 0] = v.x; sq[row][c4 + 1] = v.y;
      sq[row][c4 + 2] = v.z; sq[row][c4 + 3] = v.w;
    }
    __syncthreads();
    float s0 = 0.f, s1 = 0.f, s2 = 0.f, s3 = 0.f;
#pragma unroll
    for (int d = 0; d < 64; ++d) {
      float a = sk[ii][d];
      s0 += a * sq[jx][d];
      s1 += a * sq[jx + 16][d];
      s2 += a * sq[jx + 32][d];
      s3 += a * sq[jx + 48][d];
    }
    lg[jt * 4 + 0] = s0; lg[jt * 4 + 1] = s1; lg[jt * 4 + 2] = s2; lg[jt * 4 + 3] = s3;
    __syncthreads();
  }
  // softmax over the row's 512 logits: 16 lanes (jx) share row ii
  float mx = -1e30f;
#pragma unroll
  for (int u = 0; u < 32; ++u) mx = fmaxf(mx, lg[u]);
  for (int off = 1; off <= 8; off <<= 1) mx = fmaxf(mx, __shfl_xor(mx, off, 64));
  float sm = 0.f;
#pragma unroll
  for (int u = 0; u < 32; ++u) { lg[u] = expf(lg[u] - mx); sm += lg[u]; }
  for (int off = 1; off <= 8; off <<= 1) sm += __shfl_xor(sm, off, 64);
  float inv = 1.0f / sm;
  size_t rowbase = ((size_t)hn * 512 + it * 16 + ii) * 512;
#pragma unroll
  for (int jt = 0; jt < 8; ++jt)
#pragma unroll
    for (int qq = 0; qq < 4; ++qq) {
      int j = jt * 64 + qq * 16 + jx;
      float val = lg[jt * 4 + qq] * inv;
      probsF[rowbase + j] = val;
      probsB[rowbase + j] = f2bf(val);
    }
}

// ---------------- 6. v-GEMM: V = xbf @ Wv^T + bv, NATURAL [m][e] bf16 ----------
// 128x128 tile, BK=64, 256 thr (4 waves), wave=64x64, 4x4 mfma 16x16x32.
// global_load_lds staging; coalesced epilogue (was a 64-way 2B scatter before).
__global__ __launch_bounds__(256) void k_gemm_v(const u16* __restrict__ A,
                                                const u16* __restrict__ W,
                                                const float* __restrict__ bias,
                                                u16* __restrict__ V) {
  __shared__ __align__(16) u16 lA[128 * 64];
  __shared__ __align__(16) u16 lB[128 * 64];
  const int t = threadIdx.x;
  const int wave = t >> 6, lane = t & 63;
  const int row0 = blockIdx.x * 128, col0 = blockIdx.y * 128;
  const int wr = (wave >> 1) * 64, wc = (wave & 1) * 64;
  const int l16 = lane & 15, l4 = lane >> 4;
  float4v acc[4][4] = {};
  for (int kt = 0; kt < 768; kt += 64) {
#pragma unroll
    for (int p = 0; p < 4; ++p) {
      int c = p * 256 + t;
      int row = c >> 3, k8 = (c & 7) * 8;
      gload16(&A[(size_t)(row0 + row) * 768 + kt + k8], &lA[(size_t)c * 8]);
      gload16(&W[(size_t)(col0 + row) * 768 + kt + k8], &lB[(size_t)c * 8]);
    }
    __syncthreads();
#pragma unroll
    for (int kc = 0; kc < 64; kc += 32) {
      short8 af[4], bf[4];
#pragma unroll
      for (int i = 0; i < 4; ++i) af[i] = *(short8*)&lA[(wr + i * 16 + l16) * 64 + kc + l4 * 8];
#pragma unroll
      for (int j = 0; j < 4; ++j) bf[j] = *(short8*)&lB[(wc + j * 16 + l16) * 64 + kc + l4 * 8];
#pragma unroll
      for (int i = 0; i < 4; ++i)
#pragma unroll
        for (int j = 0; j < 4; ++j)
          acc[i][j] = __builtin_amdgcn_mfma_f32_16x16x32_bf16(af[i], bf[j], acc[i][j], 0, 0, 0);
    }
    __syncthreads();
  }
  // C/D layout: col=l16, row=l4*4+rg per 16x16 tile. Natural [m][e] store.
#pragma unroll
  for (int i = 0; i < 4; ++i)
#pragma unroll
    for (int j = 0; j < 4; ++j) {
      int e = col0 + wc + j * 16 + l16;
      float bi = bias[e];
#pragma unroll
      for (int rg = 0; rg < 4; ++rg) {
        int m = row0 + wr + i * 16 + l4 * 4 + rg;
        V[(size_t)m * 768 + e] = f2bf(acc[i][j][rg] + bi);
      }
    }
}

// ---------------- 7. context GEMM: per (r,n,h) slice, C[i][d] = P[i][:]@V[:,d] ----
// block: 256 i x 64 d, BK=64(j), 4 waves each 64i x 64d.
// lA (P rows, j-contiguous) via global_load_lds.
// lB: V natural rows [j][d] transposed into LDS [d][j'] with SWZB swizzle
//     (reg-staged ds_write_b16; bank-safe both directions, see SWZB comment).
__global__ __launch_bounds__(256) void k_gemm_ctx(const u16* __restrict__ P,
                                                  const u16* __restrict__ V,
                                                  u16* __restrict__ CTX) {
  __shared__ __align__(16) u16 lA[256 * 64];  // P rows [i][j]
  __shared__ __align__(16) u16 lB[64 * 64];   // V^T rows [d][j swizzled]
  const int t = threadIdx.x;
  const int wave = t >> 6, lane = t & 63;
  const int half = blockIdx.x;           // 0..1
  const int slice = blockIdx.y;          // ((r*4+n)*12+h)
  const int h = slice % 12, rn = slice / 12, n = rn & 3, r = rn >> 2;
  const u16* Ps = P + ((size_t)(h * 4 + n)) * 512 * 512 + (size_t)half * 256 * 512;
  // V element (j,d) of this slice lives at Vs[j*3072 + d] (natural [m][e], m=(r*512+j)*4+n)
  const u16* Vs = V + ((size_t)r * 2048 + n) * 768 + h * 64;
  const int wi = wave * 64;
  const int l16 = lane & 15, l4 = lane >> 4;
  float4v acc[4][4] = {};
  for (int jt = 0; jt < 512; jt += 64) {
#pragma unroll
    for (int p = 0; p < 8; ++p) {
      int c = p * 256 + t;
      int row = c >> 3, k8 = (c & 7) * 8;
      gload16(&Ps[(size_t)row * 512 + jt + k8], &lA[(size_t)c * 8]);
    }
#pragma unroll
    for (int p = 0; p < 2; ++p) {
      int c = p * 256 + t;
      int j = c >> 3, d8 = (c & 7) * 8;
      short8 v = *(const short8*)&Vs[(size_t)(jt + j) * 3072 + d8];
#pragma unroll
      for (int u = 0; u < 8; ++u) {
        int d = d8 + u;
        lB[d * 64 + (j ^ SWZB(d))] = (u16)v[u];
      }
    }
    __syncthreads();
#pragma unroll
    for (int kc = 0; kc < 64; kc += 32) {
      short8 af[4], bf[4];
#pragma unroll
      for (int i = 0; i < 4; ++i) af[i] = *(short8*)&lA[(wi + i * 16 + l16) * 64 + kc + l4 * 8];
#pragma unroll
      for (int j = 0; j < 4; ++j) {
        int d = j * 16 + l16;
        bf[j] = *(short8*)&lB[d * 64 + ((kc + l4 * 8) ^ SWZB(d))];
      }
#pragma unroll
      for (int i = 0; i < 4; ++i)
#pragma unroll
        for (int j = 0; j < 4; ++j)
          acc[i][j] = __builtin_amdgcn_mfma_f32_16x16x32_bf16(af[i], bf[j], acc[i][j], 0, 0, 0);
    }
    __syncthreads();
  }
#pragma unroll
  for (int i = 0; i < 4; ++i)
#pragma unroll
    for (int j = 0; j < 4; ++j) {
      int d = j * 16 + l16;
#pragma unroll
      for (int rg = 0; rg < 4; ++rg) {
        int ii = half * 256 + wi + i * 16 + l4 * 4 + rg;
        size_t m = ((size_t)(r * 512 + ii)) * 4 + n;
        CTX[m * 768 + h * 64 + d] = f2bf(acc[i][j][rg]);
      }
    }
}

// ---------------- 8. output GEMM: out = context @ Wo^T + bo (fp32) ----------------
__global__ __launch_bounds__(256) void k_gemm_out(const u16* __restrict__ A,
                                                  const u16* __restrict__ W,
                                                  const float* __restrict__ bias,
                                                  float* __restrict__ OUT) {
  __shared__ __align__(16) u16 lA[128 * 64];
  __shared__ __align__(16) u16 lB[128 * 64];
  const int t = threadIdx.x;
  const int wave = t >> 6, lane = t & 63;
  const int row0 = blockIdx.x * 128, col0 = blockIdx.y * 128;
  const int wr = (wave >> 1) * 64, wc = (wave & 1) * 64;
  const int l16 = lane & 15, l4 = lane >> 4;
  float4v acc[4][4] = {};
  for (int kt = 0; kt < 768; kt += 64) {
#pragma unroll
    for (int p = 0; p < 4; ++p) {
      int c = p * 256 + t;
      int row = c >> 3, k8 = (c & 7) * 8;
      gload16(&A[(size_t)(row0 + row) * 768 + kt + k8], &lA[(size_t)c * 8]);
      gload16(&W[(size_t)(col0 + row) * 768 + kt + k8], &lB[(size_t)c * 8]);
    }
    __syncthreads();
#pragma unroll
    for (int kc = 0; kc < 64; kc += 32) {
      short8 af[4], bf[4];
#pragma unroll
      for (int i = 0; i < 4; ++i) af[i] = *(short8*)&lA[(wr + i * 16 + l16) * 64 + kc + l4 * 8];
#pragma unroll
      for (int j = 0; j < 4; ++j) bf[j] = *(short8*)&lB[(wc + j * 16 + l16) * 64 + kc + l4 * 8];
#pragma unroll
      for (int i = 0; i < 4; ++i)
#pragma unroll
        for (int j = 0; j < 4; ++j)
          acc[i][j] = __builtin_amdgcn_mfma_f32_16x16x32_bf16(af[i], bf[j], acc[i][j], 0, 0, 0);
    }
    __syncthreads();
  }
#pragma unroll
  for (int i = 0; i < 4; ++i)
#pragma unroll
    for (int j = 0; j < 4; ++j) {
      int e = col0 + wc + j * 16 + l16;
      float bi = bias[e];
#pragma unroll
      for (int rg = 0; rg < 4; ++rg) {
        int m = row0 + wr + i * 16 + l4 * 4 + rg;
        OUT[(size_t)m * 768 + e] = acc[i][j][rg] + bi;
      }
    }
}

// ---------------- launch ----------------
// ws layout (bytes):
static const size_t WS_CTX  = 0;                       // u16[100663296]: xbf, then context
static const size_t WS_XSUM = 201326592;               // float[1572864]
static const size_t WS_Q    = WS_XSUM + 6291456;       // float[1572864]
static const size_t WS_KSUM = WS_Q + 6291456;          // float[1572864]
static const size_t WS_PBF  = WS_KSUM + 6291456;       // u16[12582912]
static const size_t WS_WVB  = WS_PBF + 25165824;       // u16[589824]
static const size_t WS_WOB  = WS_WVB + 1179648;        // u16[589824]
// total = 247726080 bytes

extern "C" void kernel_launch(void* const* d_in, const int* in_sizes, int n_in,
                              void* d_out, int out_size, void* d_ws, size_t ws_size,
                              hipStream_t stream) {
  const float* x     = (const float*)d_in[0];
  const float* query = (const float*)d_in[1];
  const float* Wq    = (const float*)d_in[2];
  const float* bq    = (const float*)d_in[3];
  const float* Wk    = (const float*)d_in[4];
  const float* bk    = (const float*)d_in[5];
  const float* Wv    = (const float*)d_in[6];
  const float* bv    = (const float*)d_in[7];
  const float* Wo    = (const float*)d_in[8];
  const float* bo    = (const float*)d_in[9];
  char* ws = (char*)d_ws;
  u16*   xbf   = (u16*)(ws + WS_CTX);
  u16*   ctxb  = xbf;                       // reused after v-GEMM consumes xbf
  float* xsum  = (float*)(ws + WS_XSUM);
  float* qws   = (float*)(ws + WS_Q);
  float* ksum  = (float*)(ws + WS_KSUM);
  u16*   pbf   = (u16*)(ws + WS_PBF);
  u16*   wvb   = (u16*)(ws + WS_WVB);
  u16*   wob   = (u16*)(ws + WS_WOB);
  float* out0   = (float*)d_out;
  float* probsF = out0 + OUT0_;
  u16*   vnat   = (u16*)d_out;              // V scratch (natural layout) in output region,
                                            // dead before final GEMM; ends before probsF.

  k_wconv<<<576, 256, 0, stream>>>(Wv, Wo, wvb, wob);
  k_xprep<<<1536, 256, 0, stream>>>(x, xbf, xsum);
  k_gemm_f32<<<dim3(12, 32), 256, 0, stream>>>(query, Wq, bq, qws, 2048, 768, 384, 1.0f);
  k_gemm_f32<<<dim3(12, 32), 256, 0, stream>>>(xsum, Wk, bk, ksum, 2048, 768, 768, 1.0f / 64.0f);
  k_logits_softmax<<<dim3(32, 48), 256, 0, stream>>>(qws, ksum, probsF, pbf);
  k_gemm_v<<<dim3(1024, 6), 256, 0, stream>>>(xbf, wvb, bv, vnat);
  k_gemm_ctx<<<dim3(2, 3072), 256, 0, stream>>>(pbf, vnat, ctxb);
  k_gemm_out<<<dim3(1024, 6), 256, 0, stream>>>(ctxb, wob, bo, out0);
}

// Round 2
// 1601.537 us; speedup vs baseline: 1.0623x; 1.0623x over previous
//
#include <hip/hip_runtime.h>
#include <stdint.h>

// MSACrossAttention on MI355X (gfx950).
// R=64 L=512 B=4 E=768 H=12 D=64 QD=384
// Key algebra: attn logits sum over r commutes with Wk: ksum=(sum_r x)@Wk.T*scaling,
// and scaling*R == 1 so bias bk passes through unscaled.
// Pipeline:
//  1. k_wconv  : Wv,Wo -> bf16
//  2. k_xprep  : xsum = sum_r x (fp32) ; xbf = bf16(x)            [ws]
//  3. k_gemm_f32: q    = query@Wq.T + bq                          [ws]
//  4. k_gemm_f32: ksum = (1/64)*(xsum@Wk.T) + bk                  [ws]
//  5. k_logits_softmax: probs fp32 -> d_out, bf16 copy -> ws
//  6. k_gemm_v : V^T = xbf@Wv.T+bv  [slice][d][j] bf16            [d_out scratch]
//     (transpose fused in epilogue via LDS round-trip, coalesced 64B stores)
//  7. k_gemm_ctx: context = probs@V (per r,n,h slice), bf16       [ws, reuses xbf]
//     (both operands staged via global_load_lds; no in-loop transpose)
//  8. k_gemm_out: out = context@Wo.T + bo (fp32)                  [d_out]
// Locality: all three big GEMMs use the T1 XCD-chunked work mapping
//   w = (bid&7)*(nwg/8) + (bid>>3)   (bid%8 == XCD round-robin)
// with the operand-sharing dimension fastest inside the chunk, so slabs are
// L2-hot (round-1 counters: k_gemm_out FETCH 598 MB vs 201 MB ideal).
// ws usage: 247,726,080 bytes.

#define R_ 64
#define L_ 512
#define B_ 4
#define E_ 768
#define H_ 12
#define D_ 64
#define P_ (L_*B_*E_)      // 1572864 elems per r-slice
#define MBIG_ (R_*L_*B_)   // 131072 rows
#define OUT0_ 100663296    // output elements (then probs)

typedef unsigned short u16;
typedef short short8 __attribute__((ext_vector_type(8)));
typedef float float4v __attribute__((ext_vector_type(4)));

__device__ __forceinline__ u16 f2bf(float f) {
  union { float f; uint32_t u; } v; v.f = f;
  return (u16)((v.u + 0x7fffu + ((v.u >> 16) & 1u)) >> 16);
}

// async global->LDS, 16B per lane. LDS dest must be wave-uniform base + lane*16,
// which holds for all call sites here (lds byte offset = c*16, c lane-contiguous).
__device__ __forceinline__ void gload16(const u16* g, u16* lds) {
  __builtin_amdgcn_global_load_lds(
      (const __attribute__((address_space(1))) u16*)g,
      (__attribute__((address_space(3))) u16*)lds, 16, 0, 0);
}

// ---------------- 1. weight convert ----------------
__global__ __launch_bounds__(256) void k_wconv(const float* __restrict__ Wv,
                                               const float* __restrict__ Wo,
                                               u16* __restrict__ Wvb,
                                               u16* __restrict__ Wob) {
  int i4 = (blockIdx.x * 256 + threadIdx.x) * 4;  // 589824 total, grid=576
  float4 v = *(const float4*)(Wv + i4);
  ushort4 b; b.x = f2bf(v.x); b.y = f2bf(v.y); b.z = f2bf(v.z); b.w = f2bf(v.w);
  *(ushort4*)(Wvb + i4) = b;
  float4 o = *(const float4*)(Wo + i4);
  ushort4 c; c.x = f2bf(o.x); c.y = f2bf(o.y); c.z = f2bf(o.z); c.w = f2bf(o.w);
  *(ushort4*)(Wob + i4) = c;
}

// ---------------- 2. x reduce-over-r + bf16 convert ----------------
__global__ __launch_bounds__(256) void k_xprep(const float* __restrict__ x,
                                               u16* __restrict__ xbf,
                                               float* __restrict__ xsum) {
  size_t p4 = ((size_t)blockIdx.x * 256 + threadIdx.x) * 4;  // grid=1536
  float sx = 0.f, sy = 0.f, sz = 0.f, sw = 0.f;
  for (int r = 0; r < R_; ++r) {
    float4 v = *(const float4*)(x + (size_t)r * P_ + p4);
    sx += v.x; sy += v.y; sz += v.z; sw += v.w;
    ushort4 b; b.x = f2bf(v.x); b.y = f2bf(v.y); b.z = f2bf(v.z); b.w = f2bf(v.w);
    *(ushort4*)(xbf + (size_t)r * P_ + p4) = b;
  }
  float4 s; s.x = sx; s.y = sy; s.z = sz; s.w = sw;
  *(float4*)(xsum + p4) = s;
}

// ---------------- 3/4. small fp32 GEMM: C = alpha*(A@W^T) + bias ----------------
// A[M][K], W[N][K], C[M][N]; block 64x64, BK=16, 256 thr, 4x4 per thread
__global__ __launch_bounds__(256) void k_gemm_f32(const float* __restrict__ A,
                                                  const float* __restrict__ W,
                                                  const float* __restrict__ bias,
                                                  float* __restrict__ C,
                                                  int M, int N, int K, float alpha) {
  __shared__ float sA[16][65], sW[16][65];
  const int t = threadIdx.x;
  const int col0 = blockIdx.x * 64, row0 = blockIdx.y * 64;
  const int tx = t & 15, ty = t >> 4;
  const int srow = t >> 2, sk4 = (t & 3) * 4;
  float acc[4][4] = {};
  for (int kt = 0; kt < K; kt += 16) {
    float4 va = *(const float4*)&A[(size_t)(row0 + srow) * K + kt + sk4];
    sA[sk4 + 0][srow] = va.x; sA[sk4 + 1][srow] = va.y;
    sA[sk4 + 2][srow] = va.z; sA[sk4 + 3][srow] = va.w;
    float4 vw = *(const float4*)&W[(size_t)(col0 + srow) * K + kt + sk4];
    sW[sk4 + 0][srow] = vw.x; sW[sk4 + 1][srow] = vw.y;
    sW[sk4 + 2][srow] = vw.z; sW[sk4 + 3][srow] = vw.w;
    __syncthreads();
#pragma unroll
    for (int k = 0; k < 16; ++k) {
      float ar[4], wr[4];
#pragma unroll
      for (int a = 0; a < 4; ++a) ar[a] = sA[k][ty + 16 * a];
#pragma unroll
      for (int b = 0; b < 4; ++b) wr[b] = sW[k][tx + 16 * b];
#pragma unroll
      for (int a = 0; a < 4; ++a)
#pragma unroll
        for (int b = 0; b < 4; ++b) acc[a][b] += ar[a] * wr[b];
    }
    __syncthreads();
  }
#pragma unroll
  for (int a = 0; a < 4; ++a)
#pragma unroll
    for (int b = 0; b < 4; ++b) {
      int col = col0 + tx + 16 * b;
      C[(size_t)(row0 + ty + 16 * a) * N + col] = alpha * acc[a][b] + bias[col];
    }
}

// ---------------- 5. logits + softmax ----------------
// block: (i-tile of 16) x (h,n). logits[i][j] = sum_d ksum[i,n,h,d]*q[j,n,h,d]
__global__ __launch_bounds__(256) void k_logits_softmax(const float* __restrict__ q,
                                                        const float* __restrict__ ksum,
                                                        float* __restrict__ probsF,
                                                        u16* __restrict__ probsB) {
  __shared__ float sk[16][65];
  __shared__ float sq[64][65];
  const int t = threadIdx.x;
  const int it = blockIdx.x;        // 0..31
  const int hn = blockIdx.y;        // 0..47 = h*4+n
  const int h = hn >> 2, n = hn & 3;
  const int ii = t >> 4, jx = t & 15;
  {
    const float* src = ksum + ((size_t)(it * 16 + ii) * 4 + n) * 768 + h * 64 + jx * 4;
    float4 v = *(const float4*)src;
    sk[ii][jx * 4 + 0] = v.x; sk[ii][jx * 4 + 1] = v.y;
    sk[ii][jx * 4 + 2] = v.z; sk[ii][jx * 4 + 3] = v.w;
  }
  float lg[32];
  for (int jt = 0; jt < 8; ++jt) {
#pragma unroll
    for (int p = 0; p < 4; ++p) {
      int c = p * 256 + t;
      int row = c >> 4, c4 = (c & 15) * 4;
      const float* src = q + ((size_t)(jt * 64 + row) * 4 + n) * 768 + h * 64 + c4;
      float4 v = *(const float4*)src;
      sq[row][c4 + 0] = v.x; sq[row][c4 + 1] = v.y;
      sq[row][c4 + 2] = v.z; sq[row][c4 + 3] = v.w;
    }
    __syncthreads();
    float s0 = 0.f, s1 = 0.f, s2 = 0.f, s3 = 0.f;
#pragma unroll
    for (int d = 0; d < 64; ++d) {
      float a = sk[ii][d];
      s0 += a * sq[jx][d];
      s1 += a * sq[jx + 16][d];
      s2 += a * sq[jx + 32][d];
      s3 += a * sq[jx + 48][d];
    }
    lg[jt * 4 + 0] = s0; lg[jt * 4 + 1] = s1; lg[jt * 4 + 2] = s2; lg[jt * 4 + 3] = s3;
    __syncthreads();
  }
  // softmax over the row's 512 logits: 16 lanes (jx) share row ii
  float mx = -1e30f;
#pragma unroll
  for (int u = 0; u < 32; ++u) mx = fmaxf(mx, lg[u]);
  for (int off = 1; off <= 8; off <<= 1) mx = fmaxf(mx, __shfl_xor(mx, off, 64));
  float sm = 0.f;
#pragma unroll
  for (int u = 0; u < 32; ++u) { lg[u] = expf(lg[u] - mx); sm += lg[u]; }
  for (int off = 1; off <= 8; off <<= 1) sm += __shfl_xor(sm, off, 64);
  float inv = 1.0f / sm;
  size_t rowbase = ((size_t)hn * 512 + it * 16 + ii) * 512;
#pragma unroll
  for (int jt = 0; jt < 8; ++jt)
#pragma unroll
    for (int qq = 0; qq < 4; ++qq) {
      int j = jt * 64 + qq * 16 + jx;
      float val = lg[jt * 4 + qq] * inv;
      probsF[rowbase + j] = val;
      probsB[rowbase + j] = f2bf(val);
    }
}

// Epilogue-transpose LDS swizzle: T[mr][ec ^ ((mr&7)<<3)].
// Write side (lanes vary ec, 4 mr rows): ~4-way, once per block.
// Read side (lanes vary n,d -> mr&7 spans 4, d spans 16): banks fully spread (~2-way).
#define ECS(mr, ec) ((ec) ^ (((mr) & 7) << 3))

// ---------------- 6. v-GEMM: V^T = (xbf @ Wv^T + bv) as [slice][d][j] bf16 -------
// 128x128 tile, BK=64, 256 thr (4 waves), wave=64x64, 4x4 mfma 16x16x32.
// global_load_lds staging; epilogue transposes the 128x128 C-tile through LDS
// (reusing the 32KB staging buffer) and stores V^T rows in 64B chunks.
// Grid: 6144 1-D, XCD-chunked, col-tile fastest (A-slab L2 reuse; Wv L2-resident).
__global__ __launch_bounds__(256) void k_gemm_v(const u16* __restrict__ A,
                                                const u16* __restrict__ W,
                                                const float* __restrict__ bias,
                                                u16* __restrict__ VT) {
  __shared__ __align__(16) u16 smem[128 * 128];   // 32 KB: lA | lB, then C-tile
  u16* lA = smem;
  u16* lB = smem + 128 * 64;
  const int t = threadIdx.x;
  const int wave = t >> 6, lane = t & 63;
  const int w = (blockIdx.x & 7) * 768 + (blockIdx.x >> 3);  // XCD chunk transform
  const int ct = w % 6, rt = w / 6;
  const int row0 = rt * 128, col0 = ct * 128;
  const int wr = (wave >> 1) * 64, wc = (wave & 1) * 64;
  const int l16 = lane & 15, l4 = lane >> 4;
  float4v acc[4][4] = {};
  for (int kt = 0; kt < 768; kt += 64) {
#pragma unroll
    for (int p = 0; p < 4; ++p) {
      int c = p * 256 + t;
      int row = c >> 3, k8 = (c & 7) * 8;
      gload16(&A[(size_t)(row0 + row) * 768 + kt + k8], &lA[(size_t)c * 8]);
      gload16(&W[(size_t)(col0 + row) * 768 + kt + k8], &lB[(size_t)c * 8]);
    }
    __syncthreads();
#pragma unroll
    for (int kc = 0; kc < 64; kc += 32) {
      short8 af[4], bf[4];
#pragma unroll
      for (int i = 0; i < 4; ++i) af[i] = *(short8*)&lA[(wr + i * 16 + l16) * 64 + kc + l4 * 8];
#pragma unroll
      for (int j = 0; j < 4; ++j) bf[j] = *(short8*)&lB[(wc + j * 16 + l16) * 64 + kc + l4 * 8];
#pragma unroll
      for (int i = 0; i < 4; ++i)
#pragma unroll
        for (int j = 0; j < 4; ++j)
          acc[i][j] = __builtin_amdgcn_mfma_f32_16x16x32_bf16(af[i], bf[j], acc[i][j], 0, 0, 0);
    }
    __syncthreads();
  }
  // ---- epilogue: C-tile (bf16, +bias) -> LDS (swizzled), then transposed stores.
  // C/D frag layout: col = l16, row = l4*4+rg per 16x16 tile.
#pragma unroll
  for (int i = 0; i < 4; ++i)
#pragma unroll
    for (int j = 0; j < 4; ++j) {
      int ec = wc + j * 16 + l16;
      float bi = bias[col0 + ec];
#pragma unroll
      for (int rg = 0; rg < 4; ++rg) {
        int mr = wr + i * 16 + l4 * 4 + rg;
        smem[mr * 128 + ECS(mr, ec)] = f2bf(acc[i][j][rg] + bi);
      }
    }
  __syncthreads();
  // block covers: r fixed, j in [j0,j0+32), n in 0..3 (m = (r*512+j)*4+n),
  // e range 128 = heads h0..h0+1, d in 0..63.
  const int r = row0 >> 11;
  const int j0 = (row0 >> 2) & 511;
  const int h0 = col0 >> 6;
#pragma unroll
  for (int up = 0; up < 2; ++up) {
    int u = up * 256 + t;          // 0..511 = (hh, d, n)
    int n = u & 3, d = (u >> 2) & 63, hh = u >> 8;
    u16* dst = VT + (((size_t)(r * 4 + n) * 12 + (h0 + hh)) * 64 + d) * 512 + j0;
    int ec = hh * 64 + d;
#pragma unroll
    for (int g = 0; g < 4; ++g) {
      short8 v;
#pragma unroll
      for (int e8 = 0; e8 < 8; ++e8) {
        int mr = (g * 8 + e8) * 4 + n;
        v[e8] = (short)smem[mr * 128 + ECS(mr, ec)];
      }
      *(short8*)(dst + g * 8) = v;
    }
  }
}

// ---------------- 7. context GEMM: per (r,n,h) slice, C[i][d] = P[i][:]@V^T[d][:] --
// block: 256 i x 64 d, BK=64(j), 4 waves each 64i x 64d; both operands gload16.
// Grid: 6144 1-D, XCD-chunked, (r, half) fastest so the 512KB P-slab (q=h*4+n)
// stays L2-hot across its 128 consecutive blocks; V^T slice L2-hot for 2nd half.
__global__ __launch_bounds__(256) void k_gemm_ctx(const u16* __restrict__ P,
                                                  const u16* __restrict__ VT,
                                                  u16* __restrict__ CTX) {
  __shared__ __align__(16) u16 lA[256 * 64];  // P rows [i][j]
  __shared__ __align__(16) u16 lB[64 * 64];   // V^T rows [d][j]
  const int t = threadIdx.x;
  const int wave = t >> 6, lane = t & 63;
  const int w = (blockIdx.x & 7) * 768 + (blockIdx.x >> 3);  // XCD chunk transform
  const int half = w & 1;                // 0..1
  const int y = w >> 1;                  // 0..3071
  const int r = y & 63, q = y >> 6;      // q = h*4+n (softmax slab index)
  const int n = q & 3, h = q >> 2;
  const u16* Ps = P + ((size_t)q) * 512 * 512 + (size_t)half * 256 * 512;
  const u16* Vs = VT + ((size_t)(r * 4 + n) * 12 + h) * 64 * 512;
  const int wi = wave * 64;
  const int l16 = lane & 15, l4 = lane >> 4;
  float4v acc[4][4] = {};
  for (int jt = 0; jt < 512; jt += 64) {
#pragma unroll
    for (int p = 0; p < 8; ++p) {
      int c = p * 256 + t;
      int row = c >> 3, k8 = (c & 7) * 8;
      gload16(&Ps[(size_t)row * 512 + jt + k8], &lA[(size_t)c * 8]);
    }
#pragma unroll
    for (int p = 0; p < 2; ++p) {
      int c = p * 256 + t;
      int row = c >> 3, k8 = (c & 7) * 8;
      gload16(&Vs[(size_t)row * 512 + jt + k8], &lB[(size_t)c * 8]);
    }
    __syncthreads();
#pragma unroll
    for (int kc = 0; kc < 64; kc += 32) {
      short8 af[4], bf[4];
#pragma unroll
      for (int i = 0; i < 4; ++i) af[i] = *(short8*)&lA[(wi + i * 16 + l16) * 64 + kc + l4 * 8];
#pragma unroll
      for (int j = 0; j < 4; ++j) bf[j] = *(short8*)&lB[(j * 16 + l16) * 64 + kc + l4 * 8];
#pragma unroll
      for (int i = 0; i < 4; ++i)
#pragma unroll
        for (int j = 0; j < 4; ++j)
          acc[i][j] = __builtin_amdgcn_mfma_f32_16x16x32_bf16(af[i], bf[j], acc[i][j], 0, 0, 0);
    }
    __syncthreads();
  }
#pragma unroll
  for (int i = 0; i < 4; ++i)
#pragma unroll
    for (int j = 0; j < 4; ++j) {
      int d = j * 16 + l16;
#pragma unroll
      for (int rg = 0; rg < 4; ++rg) {
        int ii = half * 256 + wi + i * 16 + l4 * 4 + rg;
        size_t m = ((size_t)(r * 512 + ii)) * 4 + n;
        CTX[m * 768 + h * 64 + d] = f2bf(acc[i][j][rg]);
      }
    }
}

// ---------------- 8. output GEMM: out = context @ Wo^T + bo (fp32) ----------------
// Grid: 6144 1-D, XCD-chunked, col-tile fastest (ctx-slab L2 reuse; Wo L2-resident).
__global__ __launch_bounds__(256) void k_gemm_out(const u16* __restrict__ A,
                                                  const u16* __restrict__ W,
                                                  const float* __restrict__ bias,
                                                  float* __restrict__ OUT) {
  __shared__ __align__(16) u16 lA[128 * 64];
  __shared__ __align__(16) u16 lB[128 * 64];
  const int t = threadIdx.x;
  const int wave = t >> 6, lane = t & 63;
  const int w = (blockIdx.x & 7) * 768 + (blockIdx.x >> 3);  // XCD chunk transform
  const int ct = w % 6, rt = w / 6;
  const int row0 = rt * 128, col0 = ct * 128;
  const int wr = (wave >> 1) * 64, wc = (wave & 1) * 64;
  const int l16 = lane & 15, l4 = lane >> 4;
  float4v acc[4][4] = {};
  for (int kt = 0; kt < 768; kt += 64) {
#pragma unroll
    for (int p = 0; p < 4; ++p) {
      int c = p * 256 + t;
      int row = c >> 3, k8 = (c & 7) * 8;
      gload16(&A[(size_t)(row0 + row) * 768 + kt + k8], &lA[(size_t)c * 8]);
      gload16(&W[(size_t)(col0 + row) * 768 + kt + k8], &lB[(size_t)c * 8]);
    }
    __syncthreads();
#pragma unroll
    for (int kc = 0; kc < 64; kc += 32) {
      short8 af[4], bf[4];
#pragma unroll
      for (int i = 0; i < 4; ++i) af[i] = *(short8*)&lA[(wr + i * 16 + l16) * 64 + kc + l4 * 8];
#pragma unroll
      for (int j = 0; j < 4; ++j) bf[j] = *(short8*)&lB[(wc + j * 16 + l16) * 64 + kc + l4 * 8];
#pragma unroll
      for (int i = 0; i < 4; ++i)
#pragma unroll
        for (int j = 0; j < 4; ++j)
          acc[i][j] = __builtin_amdgcn_mfma_f32_16x16x32_bf16(af[i], bf[j], acc[i][j], 0, 0, 0);
    }
    __syncthreads();
  }
#pragma unroll
  for (int i = 0; i < 4; ++i)
#pragma unroll
    for (int j = 0; j < 4; ++j) {
      int e = col0 + wc + j * 16 + l16;
      float bi = bias[e];
#pragma unroll
      for (int rg = 0; rg < 4; ++rg) {
        int m = row0 + wr + i * 16 + l4 * 4 + rg;
        OUT[(size_t)m * 768 + e] = acc[i][j][rg] + bi;
      }
    }
}

// ---------------- launch ----------------
// ws layout (bytes):
static const size_t WS_CTX  = 0;                       // u16[100663296]: xbf, then context
static const size_t WS_XSUM = 201326592;               // float[1572864]
static const size_t WS_Q    = WS_XSUM + 6291456;       // float[1572864]
static const size_t WS_KSUM = WS_Q + 6291456;          // float[1572864]
static const size_t WS_PBF  = WS_KSUM + 6291456;       // u16[12582912]
static const size_t WS_WVB  = WS_PBF + 25165824;       // u16[589824]
static const size_t WS_WOB  = WS_WVB + 1179648;        // u16[589824]
// total = 247726080 bytes

extern "C" void kernel_launch(void* const* d_in, const int* in_sizes, int n_in,
                              void* d_out, int out_size, void* d_ws, size_t ws_size,
                              hipStream_t stream) {
  const float* x     = (const float*)d_in[0];
  const float* query = (const float*)d_in[1];
  const float* Wq    = (const float*)d_in[2];
  const float* bq    = (const float*)d_in[3];
  const float* Wk    = (const float*)d_in[4];
  const float* bk    = (const float*)d_in[5];
  const float* Wv    = (const float*)d_in[6];
  const float* bv    = (const float*)d_in[7];
  const float* Wo    = (const float*)d_in[8];
  const float* bo    = (const float*)d_in[9];
  char* ws = (char*)d_ws;
  u16*   xbf   = (u16*)(ws + WS_CTX);
  u16*   ctxb  = xbf;                       // reused after v-GEMM consumes xbf
  float* xsum  = (float*)(ws + WS_XSUM);
  float* qws   = (float*)(ws + WS_Q);
  float* ksum  = (float*)(ws + WS_KSUM);
  u16*   pbf   = (u16*)(ws + WS_PBF);
  u16*   wvb   = (u16*)(ws + WS_WVB);
  u16*   wob   = (u16*)(ws + WS_WOB);
  float* out0   = (float*)d_out;
  float* probsF = out0 + OUT0_;
  u16*   vt     = (u16*)d_out;              // V^T scratch [slice][d][j] in output region,
                                            // dead before final GEMM; ends before probsF.

  k_wconv<<<576, 256, 0, stream>>>(Wv, Wo, wvb, wob);
  k_xprep<<<1536, 256, 0, stream>>>(x, xbf, xsum);
  k_gemm_f32<<<dim3(12, 32), 256, 0, stream>>>(query, Wq, bq, qws, 2048, 768, 384, 1.0f);
  k_gemm_f32<<<dim3(12, 32), 256, 0, stream>>>(xsum, Wk, bk, ksum, 2048, 768, 768, 1.0f / 64.0f);
  k_logits_softmax<<<dim3(32, 48), 256, 0, stream>>>(qws, ksum, probsF, pbf);
  k_gemm_v<<<6144, 256, 0, stream>>>(xbf, wvb, bv, vt);
  k_gemm_ctx<<<6144, 256, 0, stream>>>(pbf, vt, ctxb);
  k_gemm_out<<<6144, 256, 0, stream>>>(ctxb, wob, bo, out0);
}